// Round 5
// baseline (358.987 us; speedup 1.0000x reference)
//
#include <hip/hip_runtime.h>
#include <math.h>

#define N 4096
#define D 512
#define L 128

// ---------------- fast path ----------------
// dist via v_sad_u8 on 8-bit fixed-point (scale 16, bias 128), packed
// 4 dims per u32, transposed layouts [pd][N]. Top-16 fused into the sad
// kernel (u32 topk per lane-row), so the N x N dist matrix is never
// materialized. v_sad family measured ~4cyc/wave64 on gfx950 (R3/R4).
#define NP8 (D / 4)      // 128 packed dims (4 bytes each)
#define FBI 128          // rows per block (2 per lane, 4 waves share rows)
#define FPARTS 32        // col partitions
#define FPC (N / FPARTS) // 128 cols per block; wave covers 32 (2x16 chunks)

// ---------------- fallback path (exact f32, ~25 MB ws) ----------------
#define PARTS 16
#define PARTJ (N / PARTS)
#define TI 128
#define TJ 64
#define KD 32
#define AS_STRIDE (TI + 4)
#define BS_STRIDE (TJ + 4)
#define DS_STRIDE (TJ + 4)
#define SMEM_FLOATS (TI * DS_STRIDE)

__device__ __forceinline__ unsigned sad8(unsigned a, unsigned b, unsigned c) {
#if __has_builtin(__builtin_amdgcn_sad_u8)
  return __builtin_amdgcn_sad_u8(a, b, c);
#else
  unsigned d;
  asm("v_sad_u8 %0, %1, %2, %3" : "=v"(d) : "v"(a), "v"(b), "v"(c));
  return d;
#endif
}

// quantize+pack four consecutive dims into one u32 (u8 lanes, bias 128)
__device__ __forceinline__ unsigned pack4(float4 v) {
  int q0 = min(max(__float2int_rn(v.x * 16.0f), -128), 127) + 128;
  int q1 = min(max(__float2int_rn(v.y * 16.0f), -128), 127) + 128;
  int q2 = min(max(__float2int_rn(v.z * 16.0f), -128), 127) + 128;
  int q3 = min(max(__float2int_rn(v.w * 16.0f), -128), 127) + 128;
  return (unsigned)q0 | ((unsigned)q1 << 8) | ((unsigned)q2 << 16) |
         ((unsigned)q3 << 24);
}

// Insert v into ascending sorted tk[0..15], dropping the old max (f32).
__device__ __forceinline__ void topk_insert(float (&tk)[16], float v) {
  float x = v;
#pragma unroll
  for (int k = 0; k < 16; ++k) {
    float lo = fminf(x, tk[k]);
    float hi = fmaxf(x, tk[k]);
    tk[k] = lo;
    x = hi;
  }
}

// u32 variant.
__device__ __forceinline__ void topk_insert_u32(unsigned (&tk)[16], unsigned v) {
  unsigned x = v;
#pragma unroll
  for (int k = 0; k < 16; ++k) {
    unsigned lo = tk[k] < x ? tk[k] : x;
    unsigned hi = tk[k] < x ? x : tk[k];
    tk[k] = lo;
    x = hi;
  }
}

// rec = latent @ W + b ; grid (N/8, 2), block 256.
__global__ __launch_bounds__(256) void linear_kernel(
    const float* __restrict__ lat_test, const float* __restrict__ lat_train,
    const float* __restrict__ W, const float* __restrict__ bias,
    float* __restrict__ rec_test, float* __restrict__ rec_train) {
  const float* __restrict__ lat = blockIdx.y ? lat_train : lat_test;
  float* __restrict__ out = blockIdx.y ? rec_train : rec_test;
  const int r0 = blockIdx.x * 8;
  const int t = threadIdx.x;

  __shared__ float ls[8 * L];
  {
    float4 v = *(const float4*)(lat + (size_t)r0 * L + t * 4);
    *(float4*)&ls[t * 4] = v;
  }
  __syncthreads();

  float acc[8][2];
#pragma unroll
  for (int r = 0; r < 8; ++r) { acc[r][0] = 0.f; acc[r][1] = 0.f; }

#pragma unroll 4
  for (int l = 0; l < L; ++l) {
    float w0 = W[l * D + t];
    float w1 = W[l * D + t + 256];
#pragma unroll
    for (int r = 0; r < 8; ++r) {
      float x = ls[r * L + l];
      acc[r][0] = fmaf(x, w0, acc[r][0]);
      acc[r][1] = fmaf(x, w1, acc[r][1]);
    }
  }
  float b0 = bias[t], b1 = bias[t + 256];
#pragma unroll
  for (int r = 0; r < 8; ++r) {
    out[(size_t)(r0 + r) * D + t] = acc[r][0] + b0;
    out[(size_t)(r0 + r) * D + t + 256] = acc[r][1] + b1;
  }
}

// Quantize + pack + transpose one 64-row tile of one source matrix into
// dst[pd][N] layout. grid (N/64, 3): y=0 gt, y=1 rec_test, y=2 rec_train.
#define PKR 64
__global__ __launch_bounds__(256) void pack_kernel(
    const float* __restrict__ gt, const float* __restrict__ rec_test,
    const float* __restrict__ rec_train, unsigned* __restrict__ Gq,
    unsigned* __restrict__ Aq, unsigned* __restrict__ Tq) {
  const int which = blockIdx.y;
  const float* __restrict__ src =
      which == 0 ? gt : (which == 1 ? rec_test : rec_train);
  unsigned* __restrict__ dst = which == 0 ? Gq : (which == 1 ? Aq : Tq);
  const int i0 = blockIdx.x * PKR;
  const int tid = threadIdx.x;

  __shared__ unsigned ls[PKR][NP8 + 1];  // +1 pad -> conflict-free col reads

#pragma unroll 4
  for (int s = 0; s < 32; ++s) {
    int flat = tid + s * 256;
    int row = flat >> 7;
    int c4 = flat & 127;
    float4 v = *(const float4*)(src + (size_t)(i0 + row) * D + c4 * 4);
    ls[row][c4] = pack4(v);
  }
  __syncthreads();

#pragma unroll 4
  for (int s = 0; s < 32; ++s) {
    int flat = tid + s * 256;
    int pd = flat >> 6;
    int i = flat & 63;
    dst[(size_t)pd * N + i0 + i] = ls[i][pd];
  }
}

// ============ FUSED dist + row-topk ============
// Block: 128 rows x 128 cols of one dist matrix. 4 waves share the rows;
// wave w owns cols [jb+32w, +32) in two 16-col chunks. Lane owns 2 rows
// (uint2 A load, coalesced); B cols are wave-uniform (s_load). Each lane
// keeps a sorted u32 top-16 per row; cross-wave merge via LDS emits sorted
// per-part candidate lists. The N x N dist matrix is never written.
__global__ __launch_bounds__(256) void dist_topk_sad_kernel(
    const unsigned* __restrict__ Aq, const unsigned* __restrict__ Gq,
    const unsigned* __restrict__ Tq, unsigned* __restrict__ cand) {
  const int i0 = blockIdx.x * FBI;
  const int jb = blockIdx.y * FPC;
  const int mat = blockIdx.z;
  const unsigned* __restrict__ Bq = mat ? Tq : Gq;

  const int tid = threadIdx.x;
  const int wave = tid >> 6;
  const int lane = tid & 63;
  const int r0 = i0 + 2 * lane;  // this lane's two rows

  unsigned tk[2][16];
#pragma unroll
  for (int r = 0; r < 2; ++r)
#pragma unroll
    for (int k = 0; k < 16; ++k) tk[r][k] = 0xFFFFFFFFu;

  const unsigned* __restrict__ apb = Aq + r0;

#pragma unroll 1
  for (int c = 0; c < 2; ++c) {
    const int jc = __builtin_amdgcn_readfirstlane(jb + 32 * wave + 16 * c);
    const unsigned* ap = apb;
    const unsigned* bp = Bq + jc;  // wave-uniform -> s_load

    unsigned acc[2][16];
#pragma unroll
    for (int r = 0; r < 2; ++r)
#pragma unroll
      for (int k = 0; k < 16; ++k) acc[r][k] = 0u;

#pragma unroll 2
    for (int pd = 0; pd < NP8; ++pd) {
      uint2 a = *(const uint2*)(ap);
      uint4 b0 = *(const uint4*)(bp);
      uint4 b1 = *(const uint4*)(bp + 4);
      uint4 b2 = *(const uint4*)(bp + 8);
      uint4 b3 = *(const uint4*)(bp + 12);
      ap += N;
      bp += N;
#define SADROW(av, r)                                   \
      acc[r][0] = sad8(av, b0.x, acc[r][0]);            \
      acc[r][1] = sad8(av, b0.y, acc[r][1]);            \
      acc[r][2] = sad8(av, b0.z, acc[r][2]);            \
      acc[r][3] = sad8(av, b0.w, acc[r][3]);            \
      acc[r][4] = sad8(av, b1.x, acc[r][4]);            \
      acc[r][5] = sad8(av, b1.y, acc[r][5]);            \
      acc[r][6] = sad8(av, b1.z, acc[r][6]);            \
      acc[r][7] = sad8(av, b1.w, acc[r][7]);            \
      acc[r][8] = sad8(av, b2.x, acc[r][8]);            \
      acc[r][9] = sad8(av, b2.y, acc[r][9]);            \
      acc[r][10] = sad8(av, b2.z, acc[r][10]);          \
      acc[r][11] = sad8(av, b2.w, acc[r][11]);          \
      acc[r][12] = sad8(av, b3.x, acc[r][12]);          \
      acc[r][13] = sad8(av, b3.y, acc[r][13]);          \
      acc[r][14] = sad8(av, b3.z, acc[r][14]);          \
      acc[r][15] = sad8(av, b3.w, acc[r][15]);
      SADROW(a.x, 0)
      SADROW(a.y, 1)
#undef SADROW
    }

    // filtered inserts into the per-row top-16
#pragma unroll 1
    for (int k = 0; k < 16; ++k) {
      if (acc[0][k] < tk[0][15]) topk_insert_u32(tk[0], acc[0][k]);
      if (acc[1][k] < tk[1][15]) topk_insert_u32(tk[1], acc[1][k]);
    }
  }

  // cross-wave merge: per row, merge the 4 waves' sorted 16-lists
  __shared__ unsigned lm[FBI][4][16];  // 32 KB
#pragma unroll
  for (int r = 0; r < 2; ++r)
#pragma unroll
    for (int k4 = 0; k4 < 4; ++k4)
      *(uint4*)&lm[2 * lane + r][wave][k4 * 4] =
          make_uint4(tk[r][k4 * 4], tk[r][k4 * 4 + 1], tk[r][k4 * 4 + 2],
                     tk[r][k4 * 4 + 3]);
  __syncthreads();

  if (tid < FBI) {
    unsigned fk[16];
#pragma unroll
    for (int k = 0; k < 16; ++k) fk[k] = 0xFFFFFFFFu;
#pragma unroll 1
    for (int w2 = 0; w2 < 4; ++w2) {
      const unsigned* lp = &lm[tid][w2][0];
#pragma unroll 1
      for (int k = 0; k < 16; ++k) {
        unsigned v = lp[k];
        if (v >= fk[15]) break;  // list sorted ascending
        topk_insert_u32(fk, v);
      }
    }
    unsigned* dst =
        cand + ((size_t)(mat * FPARTS + blockIdx.y) * N + i0 + tid) * 16;
#pragma unroll
    for (int k4 = 0; k4 < 4; ++k4)
      *(uint4*)(dst + k4 * 4) = make_uint4(fk[k4 * 4], fk[k4 * 4 + 1],
                                           fk[k4 * 4 + 2], fk[k4 * 4 + 3]);
  }
}

// Merge FPARTS sorted u32 lists per row -> score. grid (2N/256).
__global__ __launch_bounds__(256) void merge_u32_kernel(
    const unsigned* __restrict__ cand, float* __restrict__ scores) {
  const int gid = blockIdx.x * 256 + threadIdx.x;
  if (gid >= 2 * N) return;
  const int m = gid >> 12;
  const int row = gid & (N - 1);

  unsigned fk[16];
#pragma unroll
  for (int k = 0; k < 16; ++k) fk[k] = 0xFFFFFFFFu;

  for (int p = 0; p < FPARTS; ++p) {
    const unsigned* lp = cand + ((size_t)(m * FPARTS + p) * N + row) * 16;
#pragma unroll 1
    for (int k = 0; k < 16; ++k) {
      unsigned v = lp[k];
      if (v >= fk[15]) break;
      topk_insert_u32(fk, v);
    }
  }
  // dist = acc/16 ; 1/dist = 16/acc (exact: acc < 2^24)
  float s = 0.f;
#pragma unroll
  for (int k = 0; k < 16; ++k) s += 16.0f / (float)fk[k];
  scores[(size_t)m * N + row] = s * (1.0f / 16.0f);
}

// ============ FALLBACK PATH (exact f32, proven) ============
__global__ __launch_bounds__(256) void dist_topk_kernel(
    const float* __restrict__ Arec, const float* __restrict__ Bgt,
    const float* __restrict__ Btr, float* __restrict__ cand) {
  const int itile = blockIdx.x;
  const int part = blockIdx.y;
  const int mat = blockIdx.z;
  const float* __restrict__ B = mat ? Btr : Bgt;
  const int i0 = itile * TI;
  const int jbase = part * PARTJ;

  __shared__ float smem[SMEM_FLOATS];
  float* As = smem;
  float* Bs = smem + KD * AS_STRIDE;
  float* distS = smem;

  const int tid = threadIdx.x;
  const int tx = tid & 15;
  const int ty = tid >> 4;
  const int srow = tid >> 1;
  const int shalf = tid & 1;
  const int scol = shalf * 32;

  float tk[16];
#pragma unroll
  for (int k = 0; k < 16; ++k) tk[k] = 3.0e38f;

  for (int jc = 0; jc < PARTJ; jc += TJ) {
    float acc[8][4];
#pragma unroll
    for (int r = 0; r < 8; ++r)
#pragma unroll
      for (int c = 0; c < 4; ++c) acc[r][c] = 0.f;

    for (int d0 = 0; d0 < D; d0 += KD) {
      __syncthreads();
#pragma unroll
      for (int s = 0; s < 4; ++s) {
        int f4 = tid + s * 256;
        int r = f4 >> 3;
        int c4 = f4 & 7;
        float4 v = *(const float4*)(Arec + (size_t)(i0 + r) * D + d0 + c4 * 4);
        As[(4 * c4 + 0) * AS_STRIDE + r] = v.x;
        As[(4 * c4 + 1) * AS_STRIDE + r] = v.y;
        As[(4 * c4 + 2) * AS_STRIDE + r] = v.z;
        As[(4 * c4 + 3) * AS_STRIDE + r] = v.w;
      }
#pragma unroll
      for (int s = 0; s < 2; ++s) {
        int f4 = tid + s * 256;
        int r = f4 >> 3;
        int c4 = f4 & 7;
        float4 v = *(const float4*)(B + (size_t)(jbase + jc + r) * D + d0 + c4 * 4);
        Bs[(4 * c4 + 0) * BS_STRIDE + r] = v.x;
        Bs[(4 * c4 + 1) * BS_STRIDE + r] = v.y;
        Bs[(4 * c4 + 2) * BS_STRIDE + r] = v.z;
        Bs[(4 * c4 + 3) * BS_STRIDE + r] = v.w;
      }
      __syncthreads();

#pragma unroll
      for (int d = 0; d < KD; ++d) {
        float4 a0 = *(const float4*)&As[d * AS_STRIDE + 8 * ty];
        float4 a1 = *(const float4*)&As[d * AS_STRIDE + 8 * ty + 4];
        float4 bv4 = *(const float4*)&Bs[d * BS_STRIDE + 4 * tx];
        float av[8] = {a0.x, a0.y, a0.z, a0.w, a1.x, a1.y, a1.z, a1.w};
        float bv[4] = {bv4.x, bv4.y, bv4.z, bv4.w};
#pragma unroll
        for (int r = 0; r < 8; ++r)
#pragma unroll
          for (int c = 0; c < 4; ++c) acc[r][c] += __builtin_fabsf(av[r] - bv[c]);
      }
    }

    __syncthreads();
#pragma unroll
    for (int r = 0; r < 8; ++r)
      *(float4*)&distS[(8 * ty + r) * DS_STRIDE + 4 * tx] =
          make_float4(acc[r][0], acc[r][1], acc[r][2], acc[r][3]);
    __syncthreads();

#pragma unroll 1
    for (int j4 = 0; j4 < 8; ++j4) {
      float4 v = *(const float4*)&distS[srow * DS_STRIDE + scol + j4 * 4];
      if (v.x < tk[15]) topk_insert(tk, v.x);
      if (v.y < tk[15]) topk_insert(tk, v.y);
      if (v.z < tk[15]) topk_insert(tk, v.z);
      if (v.w < tk[15]) topk_insert(tk, v.w);
    }
  }

  __syncthreads();
  float* mergeS = smem;
#pragma unroll
  for (int k4 = 0; k4 < 4; ++k4)
    *(float4*)&mergeS[srow * 32 + shalf * 16 + k4 * 4] =
        make_float4(tk[k4 * 4], tk[k4 * 4 + 1], tk[k4 * 4 + 2], tk[k4 * 4 + 3]);
  __syncthreads();

  if (tid < TI) {
    const float* LA = &mergeS[tid * 32];
    const float* LB = LA + 16;
    const int row = i0 + tid;
    float* dst = cand + ((size_t)((mat * PARTS + part) * N) + row) * 16;
    int ia = 0, ib = 0;
#pragma unroll 1
    for (int k = 0; k < 16; ++k) {
      float a = LA[ia < 16 ? ia : 15];
      float b = LB[ib < 16 ? ib : 15];
      bool takeA = (ib >= 16) || (ia < 16 && a <= b);
      dst[k] = takeA ? a : b;
      ia += takeA ? 1 : 0;
      ib += takeA ? 0 : 1;
    }
  }
}

__global__ __launch_bounds__(256) void merge_kernel(
    const float* __restrict__ cand, float* __restrict__ scores) {
  const int gid = blockIdx.x * 256 + threadIdx.x;
  if (gid >= 2 * N) return;
  const int m = gid >> 12;
  const int row = gid & (N - 1);

  float tk[16];
#pragma unroll
  for (int k = 0; k < 16; ++k) tk[k] = 3.0e38f;

  for (int p = 0; p < PARTS; ++p) {
    const float* lp = cand + ((size_t)((m * PARTS + p) * N) + row) * 16;
#pragma unroll 1
    for (int k = 0; k < 16; ++k) {
      float v = lp[k];
      if (v >= tk[15]) break;
      topk_insert(tk, v);
    }
  }
  float s = 0.f;
#pragma unroll
  for (int k = 0; k < 16; ++k) s += 1.0f / tk[k];
  scores[(size_t)m * N + row] = s * (1.0f / 16.0f);
}

// losses = relu(neg - pos); huber(delta=1) vs 0; mean. Single block.
__global__ __launch_bounds__(256) void loss_kernel(
    const float* __restrict__ scores, float* __restrict__ out) {
  const int tid = threadIdx.x;
  float s = 0.f;
  for (int i = tid; i < N; i += 256) {
    float l = scores[N + i] - scores[i];
    l = fmaxf(l, 0.f);
    s += (l <= 1.f) ? 0.5f * l * l : (l - 0.5f);
  }
#pragma unroll
  for (int off = 32; off > 0; off >>= 1) s += __shfl_down(s, off, 64);
  __shared__ float ws[4];
  if ((tid & 63) == 0) ws[tid >> 6] = s;
  __syncthreads();
  if (tid == 0) {
    float t = ws[0] + ws[1] + ws[2] + ws[3];
    out[0] = t * (1.0f / (float)N);
  }
}

extern "C" void kernel_launch(void* const* d_in, const int* in_sizes, int n_in,
                              void* d_out, int out_size, void* d_ws, size_t ws_size,
                              hipStream_t stream) {
  const float* gt_vals = (const float*)d_in[0];
  const float* train_latent = (const float*)d_in[1];
  const float* test_latent = (const float*)d_in[2];
  const float* W = (const float*)d_in[3];
  const float* b = (const float*)d_in[4];
  float* out = (float*)d_out;

  char* ws = (char*)d_ws;
  const size_t MB = 1048576;
  const size_t REC = 8 * MB;
  const size_t NEED_FAST = 48 * MB;

  if (ws_size >= NEED_FAST) {
    // layout: [0,2M) Aq(test), [2,4M) Tq(train), [4,6M) Gq(gt),
    // [6M,+32K) scores, [8M,24M) cand u32, [24M,32M) rec_test,
    // [32M,40M) rec_train.
    unsigned* Aq = (unsigned*)(ws);
    unsigned* Tq = (unsigned*)(ws + 2 * MB);
    unsigned* Gq = (unsigned*)(ws + 4 * MB);
    float* scores = (float*)(ws + 6 * MB);
    unsigned* cand = (unsigned*)(ws + 8 * MB);
    float* rec_test = (float*)(ws + 24 * MB);
    float* rec_train = (float*)(ws + 32 * MB);

    linear_kernel<<<dim3(N / 8, 2), 256, 0, stream>>>(
        test_latent, train_latent, W, b, rec_test, rec_train);
    pack_kernel<<<dim3(N / PKR, 3), 256, 0, stream>>>(
        gt_vals, rec_test, rec_train, Gq, Aq, Tq);
    dist_topk_sad_kernel<<<dim3(N / FBI, FPARTS, 2), 256, 0, stream>>>(
        Aq, Gq, Tq, cand);
    merge_u32_kernel<<<(2 * N) / 256, 256, 0, stream>>>(cand, scores);
    loss_kernel<<<1, 256, 0, stream>>>(scores, out);
  } else {
    float* rec_test = (float*)(ws);
    float* rec_train = (float*)(ws + REC);
    float* cand = (float*)(ws + 2 * REC);                 // 8 MB
    float* scores = (float*)(ws + 2 * REC + 8388608);     // 32 KB
    linear_kernel<<<dim3(N / 8, 2), 256, 0, stream>>>(
        test_latent, train_latent, W, b, rec_test, rec_train);
    dist_topk_kernel<<<dim3(N / TI, PARTS, 2), 256, 0, stream>>>(
        rec_test, gt_vals, rec_train, cand);
    merge_kernel<<<(2 * N) / 256, 256, 0, stream>>>(cand, scores);
    loss_kernel<<<1, 256, 0, stream>>>(scores, out);
  }
}